// Round 15
// baseline (451.063 us; speedup 1.0000x reference)
//
#include <hip/hip_runtime.h>
#include <hip/hip_bf16.h>
#include <math.h>

// ---------------------------------------------------------------------------
// KAN 2-layer forward, R15: ONE fused kernel with a MANUAL grid barrier
// (R14's hipLaunchCooperativeKernel failed to launch; replaced grid.sync()
// with a device-scope atomic barrier.  Co-residency guaranteed: 432 blocks,
// launch_bounds(512,4) -> VGPR<=128 -> 16 waves/CU; LDS 48KB -> 2 blocks/CU
// -> 512 slots >= 432, so all blocks resident at dispatch; spin is safe).
// Phases (bit-identical math/layouts to R13):
//   P1: conv  (A: x->Ag bf16 banded/swizzled; W: coef1*ssp1|sb1 -> Wg)
//   P2: gemm  (MFMA split-K=108, global_load_lds pipeline; bf16 partials)
//   P3: reduce+selu+layer2 -> out   (blocks 0..127)
// ---------------------------------------------------------------------------

#define B_DIM   128
#define IN1     3072
#define OUT1    256
#define NB      8
#define OUT2    10

#define KTOT    27648            // 9 * 3072
#define ROWB    55296            // KTOT * 2 bytes per row
#define SPLITK  108
#define BN      64
#define NBLK    432              // 4 n-tiles x 108 k-chunks

typedef short  bf16x8 __attribute__((ext_vector_type(8)));
typedef float  f32x4  __attribute__((ext_vector_type(4)));
typedef unsigned short ushort_t;
typedef unsigned int u32;

__device__ __forceinline__ ushort_t f2bf(float f) {
    union { __hip_bfloat16 h; ushort_t u; } v;
    v.h = __float2bfloat16(f);
    return v.u;
}
__device__ __forceinline__ float bf2f(ushort_t h) {
    union { float f; u32 u; } v; v.u = ((u32)h) << 16;
    return v.f;
}

__device__ __forceinline__ void gl_lds16(const void* g, void* l) {
    __builtin_amdgcn_global_load_lds(
        (const __attribute__((address_space(1))) u32*)g,
        (__attribute__((address_space(3))) u32*)l, 16, 0, 0);
}

// Manual grid barrier: monotonic counter, device scope.  Safe because all
// NBLK blocks are co-resident (see header).  cnt zeroed per launch by
// hipMemsetAsync in kernel_launch.
__device__ __forceinline__ void grid_barrier(int* cnt, int target) {
    __syncthreads();
    __threadfence();                       // release: my writes -> device
    if (threadIdx.x == 0) {
        __hip_atomic_fetch_add(cnt, 1, __ATOMIC_RELEASE, __HIP_MEMORY_SCOPE_AGENT);
        while (__hip_atomic_load(cnt, __ATOMIC_ACQUIRE, __HIP_MEMORY_SCOPE_AGENT) < target)
            __builtin_amdgcn_s_sleep(1);
    }
    __syncthreads();
    __threadfence();                       // acquire: others' writes -> me
}

// cardinal cubic B-spline basis (8 funcs) + silu, closed form (== Cox-de Boor
// recursion of the reference on the uniform extended grid [-2.2,2.2], h=0.4).
__device__ __forceinline__ void basis_silu(float x, float w[8], float& sil) {
    sil = x / (1.0f + __expf(-x));
    float u  = (x + 2.2f) * 2.5f;
    float uf = floorf(u);
    int   j  = (int)uf;
    float t  = u - uf;
    float omt = 1.0f - t;
    float t2 = t * t, t3 = t2 * t;
    float w0 = omt * omt * omt * (1.0f / 6.0f);
    float w1 = (3.0f * t3 - 6.0f * t2 + 4.0f) * (1.0f / 6.0f);
    float w2 = (-3.0f * t3 + 3.0f * t2 + 3.0f * t + 1.0f) * (1.0f / 6.0f);
    float w3 = t3 * (1.0f / 6.0f);
    bool valid = (u >= 0.0f) && (u < 11.0f);
#pragma unroll
    for (int g = 0; g < 8; ++g) {
        int m = g - j + 3;
        float v = (m == 0) ? w0 : (m == 1) ? w1 : (m == 2) ? w2 : (m == 3) ? w3 : 0.0f;
        w[g] = valid ? v : 0.0f;
    }
}

__device__ __forceinline__ float selu_f(float x) {
    const float scale = 1.0507009873554805f;
    const float alpha = 1.6732632423543772f;
    return (x > 0.0f) ? scale * x : scale * alpha * (__expf(x) - 1.0f);
}

// ---------------------------------------------------------------------------
__global__ __launch_bounds__(512, 4) void kan_fused(
        const float* __restrict__ x,
        const float* __restrict__ coef1,
        const float* __restrict__ sb1,
        const float* __restrict__ ssp1,
        const float* __restrict__ coef2,
        const float* __restrict__ sb2,
        const float* __restrict__ ssp2,
        char* __restrict__ Ag,
        char* __restrict__ Wg,
        ushort_t* __restrict__ partial,
        float* __restrict__ out,
        int* __restrict__ gbar) {
    __shared__ __align__(16) char smem[49152];
    const int tid = threadIdx.x;
    const int bid = blockIdx.x;

    // ================= P1: conversions =================
    // 960 pairs: p<192 -> A-pair (units 2p,2p+1 of 384); else W-pair (of 1536).
    // Each 256-thr half handles one unit in its 24KB LDS slice.
    for (int p = bid; p < 960; p += NBLK) {
        const int h = tid >> 8;              // half 0/1
        const int t = tid & 255;
        char* base = smem + h * 24576;

        if (p < 192) {
            // ---- A unit: (b, 1024 inputs) ----
            const int u  = 2 * p + h;        // 0..383
            const int b  = u / 3;
            const int i0 = (u % 3) * 1024;
            ushort_t (*lA)[1032] = reinterpret_cast<ushort_t(*)[1032]>(base);
            {
                const int li = t * 4;
                float4 xv = *reinterpret_cast<const float4*>(x + (size_t)b * IN1 + i0 + li);
                float xa[4] = {xv.x, xv.y, xv.z, xv.w};
#pragma unroll
                for (int pp = 0; pp < 4; ++pp) {
                    float bs[8], sil;
                    basis_silu(xa[pp], bs, sil);
#pragma unroll
                    for (int s = 0; s < 8; ++s) lA[s][li + pp] = f2bf(bs[s]);
                    lA[8][li + pp] = f2bf(sil);
                }
            }
            __syncthreads();
            char* rowp = Ag + (size_t)b * ROWB;
            const int bsw = b & 7;
#pragma unroll
            for (int r = 0; r < 5; ++r) {
                const int u2 = t + r * 256;
                if (u2 < 1152) {
                    const int s = u2 >> 7, q = u2 & 127;
                    const int ig = (i0 >> 3) + q;
                    uint4 v = *reinterpret_cast<const uint4*>(&lA[s][q * 8]);
                    *reinterpret_cast<uint4*>(rowp + (s * 48 + (ig >> 3)) * 128 +
                                              (((ig & 7) ^ bsw) << 4)) = v;
                }
            }
            __syncthreads();
        } else {
            // ---- W unit: (o, 512 inputs) ----
            const int u  = 2 * (p - 192) + h;   // 0..1535
            const int o  = u / 6;
            const int i0 = (u % 6) * 512;
            float (*cbl)[520] = reinterpret_cast<float(*)[520]>(base);  // 8x520 f32
            float* sspl = reinterpret_cast<float*>(base + 16640);      // 512 f32
            float* sbl  = reinterpret_cast<float*>(base + 16640 + 2080);
            {
                const float* cbase = coef1 + ((size_t)o * IN1 + i0) * NB;
                const int s0 = (t & 1) * 4;
                const int ih = t >> 1;
#pragma unroll
                for (int j = 0; j < 4; ++j) {
                    float4 c = *reinterpret_cast<const float4*>(cbase + j * 1024 + t * 4);
                    const int iloc = j * 128 + ih;
                    cbl[s0 + 0][iloc] = c.x;
                    cbl[s0 + 1][iloc] = c.y;
                    cbl[s0 + 2][iloc] = c.z;
                    cbl[s0 + 3][iloc] = c.w;
                }
                *reinterpret_cast<float2*>(sspl + t * 2) =
                    *reinterpret_cast<const float2*>(ssp1 + (size_t)o * IN1 + i0 + t * 2);
                *reinterpret_cast<float2*>(sbl + t * 2) =
                    *reinterpret_cast<const float2*>(sb1 + (size_t)o * IN1 + i0 + t * 2);
            }
            __syncthreads();
            char* rowp = Wg + (size_t)o * ROWB;
            const int osw = o & 7;
#pragma unroll
            for (int r = 0; r < 3; ++r) {
                const int u2 = t + r * 256;
                if (u2 < 576) {
                    const int s = u2 >> 6, q = u2 & 63;
                    const int ig = (i0 >> 3) + q;
                    ushort_t v[8];
                    if (s < 8) {
#pragma unroll
                        for (int e = 0; e < 8; ++e)
                            v[e] = f2bf(cbl[s][q * 8 + e] * sspl[q * 8 + e]);
                    } else {
#pragma unroll
                        for (int e = 0; e < 8; ++e)
                            v[e] = f2bf(sbl[q * 8 + e]);
                    }
                    *reinterpret_cast<uint4*>(rowp + (s * 48 + (ig >> 3)) * 128 +
                                              (((ig & 7) ^ osw) << 4)) =
                        *reinterpret_cast<const uint4*>(v);
                }
            }
            __syncthreads();
        }
    }

    grid_barrier(gbar, NBLK);

    // ================= P2: GEMM (bit-identical to R13 kgemm) =================
    {
        char* L[2] = { smem, smem + 24576 };   // per buf: A 16K | W 8K
        const int w = tid >> 6, l = tid & 63;
        const int nt = bid & 3, kc = bid >> 2;
        const int o0 = nt * BN;

        const int ar0 = tid >> 3;
        const int ar1 = 64 + (tid >> 3);
        const int aq  = tid & 7;
        const char* Asrc0 = Ag + (size_t)ar0 * ROWB + ((aq ^ (ar0 & 7)) << 4);
        const char* Asrc1 = Ag + (size_t)ar1 * ROWB + ((aq ^ (ar1 & 7)) << 4);
        const int wr = tid >> 3;
        const char* Wsrc = Wg + (size_t)(o0 + wr) * ROWB + ((aq ^ (wr & 7)) << 4);

#define ISSUE(ss, buf)                                                        \
        {                                                                     \
            const int cb_ = (kc * 4 + (ss)) * 128;                            \
            char* base = L[buf];                                              \
            gl_lds16(Asrc0 + cb_, base + w * 1024);                           \
            gl_lds16(Asrc1 + cb_, base + 8192 + w * 1024);                    \
            gl_lds16(Wsrc  + cb_, base + 16384 + w * 1024);                   \
        }

        f32x4 acc[2][2];
#pragma unroll
        for (int a = 0; a < 2; ++a)
#pragma unroll
            for (int bq = 0; bq < 2; ++bq) acc[a][bq] = (f32x4){0.f, 0.f, 0.f, 0.f};

        const int mq = w >> 1, nq = w & 1;
        const int r16 = l & 15, k16 = l >> 4;

        ISSUE(0, 0)
        ISSUE(1, 1)

#pragma unroll
        for (int s = 0; s < 4; ++s) {
            if (s < 3) { asm volatile("s_waitcnt vmcnt(3)" ::: "memory"); }
            else       { asm volatile("s_waitcnt vmcnt(0)" ::: "memory"); }
            __builtin_amdgcn_s_barrier();
            asm volatile("" ::: "memory");

            const char* Ab = L[s & 1];
            const char* Wb = L[s & 1] + 16384;
#pragma unroll
            for (int ks = 0; ks < 2; ++ks) {
                const int qf = ks * 4 + k16;
                bf16x8 bf[2], af[2];
#pragma unroll
                for (int bq = 0; bq < 2; ++bq) {
                    const int rn = nq * 32 + bq * 16 + r16;
                    bf[bq] = *reinterpret_cast<const bf16x8*>(Wb + rn * 128 + ((qf ^ (rn & 7)) << 4));
                }
#pragma unroll
                for (int a = 0; a < 2; ++a) {
                    const int rm = mq * 32 + a * 16 + r16;
                    af[a] = *reinterpret_cast<const bf16x8*>(Ab + rm * 128 + ((qf ^ (rm & 7)) << 4));
                }
#pragma unroll
                for (int a = 0; a < 2; ++a)
#pragma unroll
                    for (int bq = 0; bq < 2; ++bq)
                        acc[a][bq] = __builtin_amdgcn_mfma_f32_16x16x32_bf16(af[a], bf[bq], acc[a][bq], 0, 0, 0);
            }

            __builtin_amdgcn_s_barrier();
            asm volatile("" ::: "memory");
            if (s == 0) ISSUE(2, 0)
            if (s == 1) ISSUE(3, 1)
        }
#undef ISSUE

        ushort_t* pp = partial + (size_t)kc * (B_DIM * OUT1);
#pragma unroll
        for (int a = 0; a < 2; ++a) {
#pragma unroll
            for (int bq = 0; bq < 2; ++bq) {
                const int col = o0 + nq * 32 + bq * 16 + r16;
#pragma unroll
                for (int r = 0; r < 4; ++r) {
                    const int row = mq * 32 + a * 16 + k16 * 4 + r;
                    pp[(size_t)row * OUT1 + col] = f2bf(acc[a][bq][r]);
                }
            }
        }
    }

    grid_barrier(gbar, 2 * NBLK);

    // ================= P3: reduce + selu + layer2 (blocks 0..127) ===========
    if (bid < B_DIM) {
        const int b = bid;
        const int t = tid;
        const int w = t >> 6, l = t & 63;
        float* sums = reinterpret_cast<float*>(smem);            // 8 x 256 f32
        float* red  = reinterpret_cast<float*>(smem + 8192);     // 4 x 10 f32

        f32x4 s = {0.f, 0.f, 0.f, 0.f};
        const ushort_t* pb = partial + (size_t)b * OUT1 + l * 4;
#pragma unroll
        for (int c = 0; c < 13; ++c) {
            ushort4 v = *reinterpret_cast<const ushort4*>(
                pb + (size_t)(w + 8 * c) * (B_DIM * OUT1));
            s[0] += bf2f(v.x); s[1] += bf2f(v.y); s[2] += bf2f(v.z); s[3] += bf2f(v.w);
        }
        if (w < 4) {
            ushort4 v = *reinterpret_cast<const ushort4*>(
                pb + (size_t)(w + 104) * (B_DIM * OUT1));
            s[0] += bf2f(v.x); s[1] += bf2f(v.y); s[2] += bf2f(v.z); s[3] += bf2f(v.w);
        }
        *reinterpret_cast<float4*>(&sums[w * OUT1 + l * 4]) = (float4){s[0], s[1], s[2], s[3]};
        __syncthreads();

        if (t < OUT1) {
            float hv = 0.0f;
#pragma unroll
            for (int ww = 0; ww < 8; ++ww) hv += sums[ww * OUT1 + t];
            const float sh = selu_f(hv);
            float w8[8], sil;
            basis_silu(sh, w8, sil);

            float accs[OUT2];
#pragma unroll
            for (int oo = 0; oo < OUT2; ++oo) {
                const float* cp = coef2 + ((size_t)oo * OUT1 + t) * NB;
                float4 c0 = *reinterpret_cast<const float4*>(cp);
                float4 c1 = *reinterpret_cast<const float4*>(cp + 4);
                float dot = w8[0] * c0.x + w8[1] * c0.y + w8[2] * c0.z + w8[3] * c0.w +
                            w8[4] * c1.x + w8[5] * c1.y + w8[6] * c1.z + w8[7] * c1.w;
                accs[oo] = sb2[oo * OUT1 + t] * sil + ssp2[oo * OUT1 + t] * dot;
            }

#pragma unroll
            for (int oo = 0; oo < OUT2; ++oo) {
                float v = accs[oo];
#pragma unroll
                for (int off = 32; off >= 1; off >>= 1) v += __shfl_xor(v, off, 64);
                if (l == 0) red[w * OUT2 + oo] = v;
            }
        }
        __syncthreads();
        if (t < OUT2)
            out[b * OUT2 + t] = red[0 * OUT2 + t] + red[1 * OUT2 + t] +
                                red[2 * OUT2 + t] + red[3 * OUT2 + t];
    }
}

// ---------------------------------------------------------------------------
extern "C" void kernel_launch(void* const* d_in, const int* in_sizes, int n_in,
                              void* d_out, int out_size, void* d_ws, size_t ws_size,
                              hipStream_t stream) {
    const float* x     = (const float*)d_in[0];
    const float* coef1 = (const float*)d_in[1];
    const float* sb1   = (const float*)d_in[2];
    const float* ssp1  = (const float*)d_in[3];
    const float* coef2 = (const float*)d_in[4];
    const float* sb2   = (const float*)d_in[5];
    const float* ssp2  = (const float*)d_in[6];
    float* out = (float*)d_out;

    char*     Ag      = (char*)d_ws;                             // 7,077,888 B
    char*     Wg      = Ag + (size_t)B_DIM * ROWB;               // 14,155,776 B
    ushort_t* partial = (ushort_t*)(Wg + (size_t)OUT1 * ROWB);   // 7,077,888 B
    int*      gbar    = (int*)((char*)d_ws + 28311552);          // 16 B

    hipMemsetAsync(gbar, 0, 16, stream);
    kan_fused<<<NBLK, 512, 0, stream>>>(x, coef1, sb1, ssp1, coef2, sb2, ssp2,
                                        Ag, Wg, partial, out, gbar);
}

// Round 16
// 41.033 us; speedup vs baseline: 10.9926x; 10.9926x over previous
//
#include <hip/hip_runtime.h>
#include <hip/hip_bf16.h>
#include <math.h>

// ---------------------------------------------------------------------------
// KAN 2-layer forward, R16: W/A conversion FUSED INTO the GEMM (R15 verdict:
// dispatch gaps are only ~1-2us; conv's ~20us and its 21MB ws round-trip are
// the cost -> delete the round-trip).
//   D1 ktranspose: x -> xT f32 (1.5 MB)
//   D2 kgemm_fused: per chunk (32 i): 8 stages of 4 i:
//        stage: gl_lds coef1 f32 (pre-swizzled src, 8KB) + basis(xT)->A bf16
//        LDS dbuf; frag-build converts f32->bf16 (*ssp) in-reg; 1 MFMA
//        k-step/stage; + 1 silu/sb k-step per chunk.  bf16 partial[kc][b][o].
//   D3 klayer2r: 8-wave reduce (12 chunks each) + selu + layer2 -> out.
// ---------------------------------------------------------------------------

#define B_DIM   128
#define IN1     3072
#define OUT1    256
#define NB      8
#define OUT2    10

#define SPLITK  96               // chunks of 32 i
#define BN      64

typedef short  bf16x8 __attribute__((ext_vector_type(8)));
typedef float  f32x4  __attribute__((ext_vector_type(4)));
typedef unsigned short ushort_t;
typedef unsigned int u32;

__device__ __forceinline__ ushort_t f2bf(float f) {
    union { __hip_bfloat16 h; ushort_t u; } v;
    v.h = __float2bfloat16(f);
    return v.u;
}
__device__ __forceinline__ float bf2f(ushort_t h) {
    union { float f; u32 u; } v; v.u = ((u32)h) << 16;
    return v.f;
}

__device__ __forceinline__ void gl_lds16(const void* g, void* l) {
    __builtin_amdgcn_global_load_lds(
        (const __attribute__((address_space(1))) u32*)g,
        (__attribute__((address_space(3))) u32*)l, 16, 0, 0);
}

__device__ __forceinline__ bf16x8 pack8(float a0, float a1, float a2, float a3,
                                        float a4, float a5, float a6, float a7) {
    union { ushort_t u[8]; bf16x8 v; } r;
    r.u[0] = f2bf(a0); r.u[1] = f2bf(a1); r.u[2] = f2bf(a2); r.u[3] = f2bf(a3);
    r.u[4] = f2bf(a4); r.u[5] = f2bf(a5); r.u[6] = f2bf(a6); r.u[7] = f2bf(a7);
    return r.v;
}

// cardinal cubic B-spline basis (8 funcs) + silu, closed form (== Cox-de Boor
// recursion of the reference on the uniform extended grid [-2.2,2.2], h=0.4).
__device__ __forceinline__ void basis_silu(float x, float w[8], float& sil) {
    sil = x / (1.0f + __expf(-x));
    float u  = (x + 2.2f) * 2.5f;
    float uf = floorf(u);
    int   j  = (int)uf;
    float t  = u - uf;
    float omt = 1.0f - t;
    float t2 = t * t, t3 = t2 * t;
    float w0 = omt * omt * omt * (1.0f / 6.0f);
    float w1 = (3.0f * t3 - 6.0f * t2 + 4.0f) * (1.0f / 6.0f);
    float w2 = (-3.0f * t3 + 3.0f * t2 + 3.0f * t + 1.0f) * (1.0f / 6.0f);
    float w3 = t3 * (1.0f / 6.0f);
    bool valid = (u >= 0.0f) && (u < 11.0f);
#pragma unroll
    for (int g = 0; g < 8; ++g) {
        int m = g - j + 3;
        float v = (m == 0) ? w0 : (m == 1) ? w1 : (m == 2) ? w2 : (m == 3) ? w3 : 0.0f;
        w[g] = valid ? v : 0.0f;
    }
}

__device__ __forceinline__ float selu_f(float x) {
    const float scale = 1.0507009873554805f;
    const float alpha = 1.6732632423543772f;
    return (x > 0.0f) ? scale * x : scale * alpha * (__expf(x) - 1.0f);
}

// ---------------------------------------------------------------------------
// D1: transpose x (128,3072) -> xT (3072,128)
// ---------------------------------------------------------------------------
__global__ __launch_bounds__(256) void ktranspose(const float* __restrict__ x,
                                                  float* __restrict__ xT) {
    __shared__ float t[32][33];
    int bx = blockIdx.x, by = blockIdx.y;
    int tx = threadIdx.x, ty = threadIdx.y;
#pragma unroll
    for (int k = 0; k < 4; ++k)
        t[ty + k * 8][tx] = x[(by * 32 + ty + k * 8) * IN1 + bx * 32 + tx];
    __syncthreads();
#pragma unroll
    for (int k = 0; k < 4; ++k)
        xT[(bx * 32 + ty + k * 8) * B_DIM + by * 32 + tx] = t[tx][ty + k * 8];
}

// ---------------------------------------------------------------------------
// D2: fused conv+GEMM.  grid (4 nt, 96 kc), 512 thr (8 waves).
// LDS map (bytes):
//   Ab0 0..10240, Ab1 10240..20480          (128 rows x 80B: 4x16B basis+pad)
//   Wb0 20480..28672, Wb1 28672..36864      (64 o x 128B: 8 xor-swz 16B units)
//   silb 36864..47104                       (128 rows x 80B: 32 bf16 + pad)
//   sspb 47104..55808                       (64 o x 136B: 32 f32 + pad)
//   sbb  55808..65024                       (64 o x 144B: 32 f32 + pad)
// ---------------------------------------------------------------------------
__global__ __launch_bounds__(512, 2) void kgemm_fused(
        const float* __restrict__ xT,
        const float* __restrict__ coef1,
        const float* __restrict__ sb1,
        const float* __restrict__ ssp1,
        ushort_t* __restrict__ partial) {
    __shared__ __align__(16) char smem[65024];
    char* Ab0 = smem;
    char* Ab1 = smem + 10240;
    char* Wb0 = smem + 20480;
    char* Wb1 = smem + 28672;
    char* silb = smem + 36864;
    char* sspb = smem + 47104;
    char* sbb  = smem + 55808;

    const int tid = threadIdx.x;
    const int w = tid >> 6, l = tid & 63;
    const int nt = blockIdx.x, kc = blockIdx.y;
    const int o0  = nt * BN;
    const int i0c = kc * 32;
    const int mq = w >> 1, nq = w & 1;
    const int r16 = l & 15, k16 = l >> 4;

    // A-compute mapping
    const int ab  = tid & 127;
    const int ail = tid >> 7;            // 0..3
    // W gl_lds mapping (pre-swizzled source; linear dest)
    const int wo  = tid >> 3;            // 0..63
    const int wul = (tid & 7) ^ (wo & 7);

#define WISSUE(ss, Wdst)                                                       \
    {                                                                          \
        const float* gsrc = coef1 +                                            \
            ((size_t)(o0 + wo) * IN1 + (i0c + (ss) * 4 + (wul >> 1))) * 8 +    \
            (wul & 1) * 4;                                                     \
        gl_lds16(gsrc, (Wdst) + w * 1024);                                     \
    }

#define ACOMPUTE(ss, Adst)                                                     \
    {                                                                          \
        float xv = xT[(size_t)(i0c + (ss) * 4 + ail) * B_DIM + ab];            \
        float bs[8], sil;                                                      \
        basis_silu(xv, bs, sil);                                               \
        ushort_t v[8];                                                         \
        v[0]=f2bf(bs[0]); v[1]=f2bf(bs[1]); v[2]=f2bf(bs[2]); v[3]=f2bf(bs[3]);\
        v[4]=f2bf(bs[4]); v[5]=f2bf(bs[5]); v[6]=f2bf(bs[6]); v[7]=f2bf(bs[7]);\
        *reinterpret_cast<uint4*>((Adst) + ab * 80 + ail * 16) =               \
            *reinterpret_cast<const uint4*>(v);                                \
        *reinterpret_cast<ushort_t*>(silb + ab * 80 + ((ss) * 4 + ail) * 2) =  \
            f2bf(sil);                                                         \
    }

    f32x4 acc[2][2];
#pragma unroll
    for (int a = 0; a < 2; ++a)
#pragma unroll
        for (int bq = 0; bq < 2; ++bq) acc[a][bq] = (f32x4){0.f, 0.f, 0.f, 0.f};

    // ---- prologue: ssp/sb chunk staging + W(0)/A(0) ----
    WISSUE(0, Wb0)
    {
        const int o = tid >> 3, iw = tid & 7;
        const size_t e = (size_t)(o0 + o) * IN1 + i0c + iw * 4;
        float4 sv = *reinterpret_cast<const float4*>(ssp1 + e);
        *reinterpret_cast<float2*>(sspb + o * 136 + iw * 16)     = (float2){sv.x, sv.y};
        *reinterpret_cast<float2*>(sspb + o * 136 + iw * 16 + 8) = (float2){sv.z, sv.w};
        float4 bv = *reinterpret_cast<const float4*>(sb1 + e);
        *reinterpret_cast<float4*>(sbb + o * 144 + iw * 16) = bv;
    }
    ACOMPUTE(0, Ab0)
    asm volatile("s_waitcnt vmcnt(0)" ::: "memory");
    __syncthreads();

    // ---- 8 stages ----
#pragma unroll 1
    for (int s = 0; s < 8; ++s) {
        char* Acur = (s & 1) ? Ab1 : Ab0;
        char* Wcur = (s & 1) ? Wb1 : Wb0;
        char* Anxt = (s & 1) ? Ab0 : Ab1;
        char* Wnxt = (s & 1) ? Wb0 : Wb1;

        if (s < 7) {
            WISSUE(s + 1, Wnxt)
            ACOMPUTE(s + 1, Anxt)
        }

        // MFMA k-step on current buffers
        {
            bf16x8 bfr[2], af[2];
#pragma unroll
            for (int bq = 0; bq < 2; ++bq) {
                const int ol = nq * 32 + bq * 16 + r16;
                const int u0 = (k16 * 2)     ^ (ol & 7);
                const int u1 = (k16 * 2 + 1) ^ (ol & 7);
                f32x4 wa = *reinterpret_cast<const f32x4*>(Wcur + ol * 128 + u0 * 16);
                f32x4 wb = *reinterpret_cast<const f32x4*>(Wcur + ol * 128 + u1 * 16);
                float sv = *reinterpret_cast<const float*>(sspb + ol * 136 + (s * 4 + k16) * 4);
                bfr[bq] = pack8(wa[0] * sv, wa[1] * sv, wa[2] * sv, wa[3] * sv,
                                wb[0] * sv, wb[1] * sv, wb[2] * sv, wb[3] * sv);
            }
#pragma unroll
            for (int a = 0; a < 2; ++a) {
                const int rm = mq * 32 + a * 16 + r16;
                af[a] = *reinterpret_cast<const bf16x8*>(Acur + rm * 80 + k16 * 16);
            }
#pragma unroll
            for (int a = 0; a < 2; ++a)
#pragma unroll
                for (int bq = 0; bq < 2; ++bq)
                    acc[a][bq] = __builtin_amdgcn_mfma_f32_16x16x32_bf16(af[a], bfr[bq], acc[a][bq], 0, 0, 0);
        }

        if (s < 7) {
            asm volatile("s_waitcnt vmcnt(0)" ::: "memory");
            __syncthreads();
        }
    }

    // ---- silu/sb k-step (reads persistent silb/sbb; no barrier needed:
    //      last sil write was covered by stage-6's barrier) ----
    {
        bf16x8 bfr[2], af[2];
#pragma unroll
        for (int bq = 0; bq < 2; ++bq) {
            const int ol = nq * 32 + bq * 16 + r16;
            f32x4 s0 = *reinterpret_cast<const f32x4*>(sbb + ol * 144 + k16 * 32);
            f32x4 s1 = *reinterpret_cast<const f32x4*>(sbb + ol * 144 + k16 * 32 + 16);
            bfr[bq] = pack8(s0[0], s0[1], s0[2], s0[3], s1[0], s1[1], s1[2], s1[3]);
        }
#pragma unroll
        for (int a = 0; a < 2; ++a) {
            const int rm = mq * 32 + a * 16 + r16;
            af[a] = *reinterpret_cast<const bf16x8*>(silb + rm * 80 + k16 * 16);
        }
#pragma unroll
        for (int a = 0; a < 2; ++a)
#pragma unroll
            for (int bq = 0; bq < 2; ++bq)
                acc[a][bq] = __builtin_amdgcn_mfma_f32_16x16x32_bf16(af[a], bfr[bq], acc[a][bq], 0, 0, 0);
    }

    // ---- epilogue: bf16 partial [kc][b][o] ----
    ushort_t* pp = partial + (size_t)kc * (B_DIM * OUT1);
#pragma unroll
    for (int a = 0; a < 2; ++a) {
#pragma unroll
        for (int bq = 0; bq < 2; ++bq) {
            const int col = o0 + nq * 32 + bq * 16 + r16;
#pragma unroll
            for (int r = 0; r < 4; ++r) {
                const int row = mq * 32 + a * 16 + k16 * 4 + r;
                pp[(size_t)row * OUT1 + col] = f2bf(acc[a][bq][r]);
            }
        }
    }
#undef WISSUE
#undef ACOMPUTE
}

// ---------------------------------------------------------------------------
// D3: klayer2r — one block per b, 512 thr (8 waves), 12 chunks per wave.
// ---------------------------------------------------------------------------
__global__ __launch_bounds__(512) void klayer2r(const ushort_t* __restrict__ partial,
                                                const float* __restrict__ coef2,
                                                const float* __restrict__ sb2,
                                                const float* __restrict__ ssp2,
                                                float* __restrict__ out) {
    const int b = blockIdx.x;
    const int t = threadIdx.x;
    const int w = t >> 6, l = t & 63;
    __shared__ float sums[8][OUT1];
    __shared__ float red[4][OUT2];

    f32x4 s = {0.f, 0.f, 0.f, 0.f};
    const ushort_t* pb = partial + (size_t)b * OUT1 + l * 4;
#pragma unroll
    for (int c = 0; c < 12; ++c) {
        ushort4 v = *reinterpret_cast<const ushort4*>(
            pb + (size_t)(w + 8 * c) * (B_DIM * OUT1));
        s[0] += bf2f(v.x); s[1] += bf2f(v.y); s[2] += bf2f(v.z); s[3] += bf2f(v.w);
    }
    *reinterpret_cast<float4*>(&sums[w][l * 4]) = (float4){s[0], s[1], s[2], s[3]};
    __syncthreads();

    if (t < OUT1) {
        float hv = 0.0f;
#pragma unroll
        for (int ww = 0; ww < 8; ++ww) hv += sums[ww][t];
        const float sh = selu_f(hv);
        float w8[8], sil;
        basis_silu(sh, w8, sil);

        float accs[OUT2];
#pragma unroll
        for (int oo = 0; oo < OUT2; ++oo) {
            const float* cp = coef2 + ((size_t)oo * OUT1 + t) * NB;
            float4 c0 = *reinterpret_cast<const float4*>(cp);
            float4 c1 = *reinterpret_cast<const float4*>(cp + 4);
            float dot = w8[0] * c0.x + w8[1] * c0.y + w8[2] * c0.z + w8[3] * c0.w +
                        w8[4] * c1.x + w8[5] * c1.y + w8[6] * c1.z + w8[7] * c1.w;
            accs[oo] = sb2[oo * OUT1 + t] * sil + ssp2[oo * OUT1 + t] * dot;
        }

#pragma unroll
        for (int oo = 0; oo < OUT2; ++oo) {
            float v = accs[oo];
#pragma unroll
            for (int off = 32; off >= 1; off >>= 1) v += __shfl_xor(v, off, 64);
            if (l == 0) red[w][oo] = v;
        }
    }
    __syncthreads();
    if (t < OUT2)
        out[b * OUT2 + t] = red[0][t] + red[1][t] + red[2][t] + red[3][t];
}

// ---------------------------------------------------------------------------
extern "C" void kernel_launch(void* const* d_in, const int* in_sizes, int n_in,
                              void* d_out, int out_size, void* d_ws, size_t ws_size,
                              hipStream_t stream) {
    const float* x     = (const float*)d_in[0];
    const float* coef1 = (const float*)d_in[1];
    const float* sb1   = (const float*)d_in[2];
    const float* ssp1  = (const float*)d_in[3];
    const float* coef2 = (const float*)d_in[4];
    const float* sb2   = (const float*)d_in[5];
    const float* ssp2  = (const float*)d_in[6];
    float* out = (float*)d_out;

    float*    xT      = (float*)d_ws;                                // 1,572,864 B
    ushort_t* partial = (ushort_t*)((char*)d_ws + 1572864);          // 6,291,456 B

    ktranspose<<<dim3(96, 4), dim3(32, 8), 0, stream>>>(x, xT);
    kgemm_fused<<<dim3(OUT1 / BN, SPLITK), 512, 0, stream>>>(xT, coef1, sb1, ssp1, partial);
    klayer2r<<<B_DIM, 512, 0, stream>>>(partial, coef2, sb2, ssp2, out);
}